// Round 10
// baseline (278.672 us; speedup 1.0000x reference)
//
#include <hip/hip_runtime.h>
#include <hip/hip_bf16.h>

// Established rounds 0-9: inputs fp32 (detector=insurance), output fp32.
// R5/R6: VALU->MFMA everywhere. R7: attn reg-prefetch 121->~65us. R8: fold
// MFMA 68->~8us, but fusing x-conversion into gemm1 cost ~25us (fp32 re-fetch
// x16 + redundant VALU) -> R9: re-separate convert_x + reg-prefetch dbuf in
// both GEMMs (the R7 fix, applied to the new #1 latency-bound kernel).
#define B_  2
#define T_  2048
#define D_  1024
#define H_  16
#define DH_ 64
#define R_  32
#define BT_ (B_*T_)          // 4096
#define BH_ (B_*H_)          // 32

typedef unsigned short u16;
typedef unsigned int   u32;
typedef __attribute__((ext_vector_type(8))) short bhalf8;   // 8 bf16 = 4 VGPRs
typedef __attribute__((ext_vector_type(4))) float floatx4;  // MFMA C/D

// Workspace layout (bytes). Total ~38 MB.
#define WSB_FLAG  0
#define WSB_XB    256                        // bf16 x     (4096,1024)  8 MB
#define WSB_WCATT (WSB_XB    + 8388608)      // bf16 WcatT (2048,1024)  4 MB
#define WSB_QL    (WSB_WCATT + 4194304)      // bf16 (B,H,T,R)          4 MB
#define WSB_KL    (WSB_QL    + 4194304)      // bf16 (B,H,T,R)          4 MB
#define WSB_VT    (WSB_KL    + 4194304)      // bf16 (B,H,DH,T)         8 MB
#define WSB_YB    (WSB_VT    + 8388608)      // bf16 y     (B,T,D)      8 MB
#define WSB_WOT   (WSB_YB    + 8388608)      // bf16 WoT   (1024,1024)  2 MB

#define NEG_ -1.0e30f

__device__ __forceinline__ float bfs(u16 s) {
    union { u32 i; float f; } w; w.i = ((u32)s) << 16; return w.f;
}
__device__ __forceinline__ u16 tob(float f) {
    __hip_bfloat16 h = __float2bfloat16(f);   // RNE
    return *(u16*)&h;
}
__device__ __forceinline__ u32 pack2(float a, float b) {
    return (u32)tob(a) | ((u32)tob(b) << 16);
}

// ---------------------------------------------------------------------------
// Kernel D: detect input dtype (1 = bf16, 0 = fp32) — insurance only.
// ---------------------------------------------------------------------------
__global__ __launch_bounds__(64) void detect_dtype(const u32* __restrict__ xw,
                                                   int* __restrict__ flag)
{
    const int tid = threadIdx.x;
    int hits = 0;
    for (int i = tid; i < 512; i += 64) {
        const u32 w = xw[i];
        const u32 h = w & 0xFFFFu;
        const u32 e = (h >> 7) & 0xFFu;
        if (h == 0u || (e >= 100u && e <= 150u)) ++hits;
    }
    #pragma unroll
    for (int off = 32; off; off >>= 1) hits += __shfl_down(hits, off, 64);
    if (tid == 0) *flag = (hits >= 300) ? 1 : 0;
}

// ---------------------------------------------------------------------------
// Kernel C: x -> xb bf16 (8 elems/thread). HBM-bound, ~24 MB traffic.
// ---------------------------------------------------------------------------
__global__ __launch_bounds__(256) void convert_x(
    const void* __restrict__ x, u16* __restrict__ xb,
    const int* __restrict__ flag)
{
    const int isbf = *flag;
    const int e = blockIdx.x * 256 + threadIdx.x;  // over 524288 (x8 elems)
    if (isbf) {
        ((uint4*)xb)[e] = ((const uint4*)x)[e];
    } else {
        float4 a0 = ((const float4*)x)[2*e];
        float4 a1 = ((const float4*)x)[2*e + 1];
        uint4 o;
        o.x = pack2(a0.x, a0.y); o.y = pack2(a0.z, a0.w);
        o.z = pack2(a1.x, a1.y); o.w = pack2(a1.z, a1.w);
        ((uint4*)xb)[e] = o;
    }
}

// ---------------------------------------------------------------------------
// Kernel 0: fold via MFMA. Per head h: Cq(32x1024) = Aq_h^T(32x64) @ Wq_h(64x1024)
// with m=r, k=dh, n=d. B operand (Wqkv slice) is k-contiguous natively.
// ---------------------------------------------------------------------------
__global__ __launch_bounds__(256) void fold_mfma(
    const void* __restrict__ Wqkv, const void* __restrict__ Wq_lsr,
    const void* __restrict__ Wk_lsr, const void* __restrict__ core,
    u16* __restrict__ WcatT, const int* __restrict__ flag)
{
    __shared__ __align__(16) u16 Bq[128 * 72];   // [n=d][k=dh]
    __shared__ __align__(16) u16 Bk[128 * 72];
    __shared__ __align__(16) u16 Aq[32 * 72];    // [m=r][k=dh]
    __shared__ __align__(16) u16 Ak[32 * 72];
    const int isbf = *flag;
    const int tid  = threadIdx.x;
    const int lane = tid & 63;
    const int w    = tid >> 6;
    const int n16  = lane & 15;
    const int q4   = lane >> 4;
    const int h    = blockIdx.y;        // 0..15
    const int d0   = blockIdx.x * 128;  // 0..896

    #pragma unroll
    for (int p = 0; p < 8; ++p) {
        const int e  = tid + p * 256;
        const int r  = e & 31, dh = e >> 5;
        float aq, ak;
        if (isbf) {
            aq = bfs(((const u16*)Wq_lsr)[(h*DH_ + dh)*R_ + r]);
            ak = bfs(((const u16*)Wk_lsr)[(h*DH_ + dh)*R_ + r]);
        } else {
            aq = ((const float*)Wq_lsr)[(h*DH_ + dh)*R_ + r];
            ak = ((const float*)Wk_lsr)[(h*DH_ + dh)*R_ + r];
        }
        Aq[r * 72 + dh] = tob(aq);
        Ak[r * 72 + dh] = tob(ak);
    }
    #pragma unroll
    for (int p = 0; p < 8; ++p) {
        const int e  = tid + p * 256;      // 0..2047
        const int n  = e >> 4, ch = e & 15;
        if (isbf) {
            uint2 wq = *(const uint2*)((const u16*)Wqkv + (size_t)(d0+n)*(3*D_) + h*DH_ + ch*4);
            uint2 wk = *(const uint2*)((const u16*)Wqkv + (size_t)(d0+n)*(3*D_) + D_ + h*DH_ + ch*4);
            *(uint2*)&Bq[n * 72 + ch*4] = wq;
            *(uint2*)&Bk[n * 72 + ch*4] = wk;
        } else {
            float4 fq = *(const float4*)((const float*)Wqkv + (size_t)(d0+n)*(3*D_) + h*DH_ + ch*4);
            float4 fk = *(const float4*)((const float*)Wqkv + (size_t)(d0+n)*(3*D_) + D_ + h*DH_ + ch*4);
            uint2 oq, ok;
            oq.x = pack2(fq.x, fq.y); oq.y = pack2(fq.z, fq.w);
            ok.x = pack2(fk.x, fk.y); ok.y = pack2(fk.z, fk.w);
            *(uint2*)&Bq[n * 72 + ch*4] = oq;
            *(uint2*)&Bk[n * 72 + ch*4] = ok;
        }
    }
    __syncthreads();

    floatx4 accq[2][2], acck[2][2];
    #pragma unroll
    for (int mi = 0; mi < 2; ++mi)
        #pragma unroll
        for (int ni = 0; ni < 2; ++ni) { accq[mi][ni] = (floatx4)(0.f); acck[mi][ni] = (floatx4)(0.f); }

    #pragma unroll
    for (int kk = 0; kk < 2; ++kk) {
        bhalf8 aqf[2], akf[2], bqf[2], bkf[2];
        #pragma unroll
        for (int mi = 0; mi < 2; ++mi) {
            aqf[mi] = *(const bhalf8*)&Aq[(mi*16 + n16) * 72 + kk*32 + q4*8];
            akf[mi] = *(const bhalf8*)&Ak[(mi*16 + n16) * 72 + kk*32 + q4*8];
        }
        #pragma unroll
        for (int ni = 0; ni < 2; ++ni) {
            bqf[ni] = *(const bhalf8*)&Bq[(w*32 + ni*16 + n16) * 72 + kk*32 + q4*8];
            bkf[ni] = *(const bhalf8*)&Bk[(w*32 + ni*16 + n16) * 72 + kk*32 + q4*8];
        }
        #pragma unroll
        for (int mi = 0; mi < 2; ++mi)
            #pragma unroll
            for (int ni = 0; ni < 2; ++ni) {
                accq[mi][ni] = __builtin_amdgcn_mfma_f32_16x16x32_bf16(aqf[mi], bqf[ni], accq[mi][ni], 0, 0, 0);
                acck[mi][ni] = __builtin_amdgcn_mfma_f32_16x16x32_bf16(akf[mi], bkf[ni], acck[mi][ni], 0, 0, 0);
            }
    }

    const float scale = 0.17677669529663687f;  // 1/sqrt(32)
    #pragma unroll
    for (int mi = 0; mi < 2; ++mi) {
        #pragma unroll
        for (int rr = 0; rr < 4; ++rr) {
            const int r = mi*16 + q4*4 + rr;
            const float cc = (isbf ? bfs(((const u16*)core)[h*R_ + r])
                                   : ((const float*)core)[h*R_ + r]) * scale;
            #pragma unroll
            for (int ni = 0; ni < 2; ++ni) {
                const int d = d0 + w*32 + ni*16 + n16;
                WcatT[(size_t)(h*R_ + r) * D_ + d]       = tob(accq[mi][ni][rr] * cc);
                WcatT[(size_t)(512 + h*R_ + r) * D_ + d] = tob(acck[mi][ni][rr]);
            }
        }
    }
}

// ---------------------------------------------------------------------------
// Kernel T: generic transposing convert (fp32/bf16 -> bf16), 64x64 tiles.
// ---------------------------------------------------------------------------
__global__ __launch_bounds__(256) void convert_T(
    const void* __restrict__ src, u16* __restrict__ dst,
    int srcStride, int srcColOff, int dstRowOff, const int* __restrict__ flag)
{
    __shared__ __align__(16) u16 tile[64 * 72];
    const int isbf = *flag;
    const int tid = threadIdx.x;
    const int j0  = blockIdx.x * 64;
    const int i0  = blockIdx.y * 64;
    #pragma unroll
    for (int p = 0; p < 2; ++p) {
        const int e = tid + p * 256;
        const int r = e >> 3, ch = e & 7;
        if (isbf) {
            uint4 w = *(const uint4*)((const u16*)src + (size_t)(i0 + r) * srcStride + srcColOff + j0 + ch*8);
            *(uint4*)&tile[r * 72 + ch*8] = w;
        } else {
            const float* s = (const float*)src + (size_t)(i0 + r) * srcStride + srcColOff + j0 + ch*8;
            float4 a0 = *(const float4*)s;
            float4 a1 = *(const float4*)(s + 4);
            uint4 o;
            o.x = pack2(a0.x, a0.y); o.y = pack2(a0.z, a0.w);
            o.z = pack2(a1.x, a1.y); o.w = pack2(a1.z, a1.w);
            *(uint4*)&tile[r * 72 + ch*8] = o;
        }
    }
    __syncthreads();
    #pragma unroll
    for (int p = 0; p < 2; ++p) {
        const int e = tid + p * 256;
        const int c = e >> 3, ch = e & 7;
        u16 tmp[8];
        #pragma unroll
        for (int j = 0; j < 8; ++j) tmp[j] = tile[(ch*8 + j) * 72 + c];
        *(uint4*)(dst + (size_t)(dstRowOff + j0 + c) * D_ + i0 + ch*8) = *(uint4*)tmp;
    }
}

// ---------------------------------------------------------------------------
// Kernel 1: MFMA gemm1  xb(4096,1024) @ WcatT^T -> ql/kl + v_t.
// 128x128 tile, BK=64, 4 waves 2x2. Register dbuf prefetch: stage-from-regs,
// issue next tile's global loads, barrier, compute -> latency overlapped.
// ---------------------------------------------------------------------------
__global__ __launch_bounds__(256) void gemm1_mfma(
    const u16* __restrict__ xb, const u16* __restrict__ WcatT,
    u16* __restrict__ ql, u16* __restrict__ kl, u16* __restrict__ v_t)
{
    __shared__ __align__(16) u16 As[128 * 72];
    __shared__ __align__(16) u16 Bs[128 * 72];
    const int tid  = threadIdx.x;
    const int lane = tid & 63;
    const int w    = tid >> 6;
    const int n16  = lane & 15;
    const int q4   = lane >> 4;
    const int wx   = w & 1;          // n-half
    const int wy   = w >> 1;         // m-half
    const int bm   = blockIdx.y * 128;
    const int bn   = blockIdx.x * 128;
    const int rs   = tid >> 3;       // staging row base 0..31
    const int ch8  = (tid & 7) * 8;  // staging col (u16)

    uint4 pa[4], pb[4];
    #pragma unroll
    for (int p = 0; p < 4; ++p) {
        pa[p] = *(const uint4*)(xb    + (size_t)(bm + rs + 32*p) * D_ + ch8);
        pb[p] = *(const uint4*)(WcatT + (size_t)(bn + rs + 32*p) * D_ + ch8);
    }

    floatx4 acc[4][4];
    #pragma unroll
    for (int i = 0; i < 4; ++i)
        #pragma unroll
        for (int j = 0; j < 4; ++j) acc[i][j] = (floatx4)(0.f);

    for (int kt = 0; kt < D_; kt += 64) {
        __syncthreads();
        #pragma unroll
        for (int p = 0; p < 4; ++p) {
            *(uint4*)&As[(rs + 32*p) * 72 + ch8] = pa[p];
            *(uint4*)&Bs[(rs + 32*p) * 72 + ch8] = pb[p];
        }
        if (kt + 64 < D_) {
            #pragma unroll
            for (int p = 0; p < 4; ++p) {
                pa[p] = *(const uint4*)(xb    + (size_t)(bm + rs + 32*p) * D_ + kt + 64 + ch8);
                pb[p] = *(const uint4*)(WcatT + (size_t)(bn + rs + 32*p) * D_ + kt + 64 + ch8);
            }
        }
        __syncthreads();
        #pragma unroll
        for (int kk = 0; kk < 2; ++kk) {
            bhalf8 a[4], b[4];
            #pragma unroll
            for (int mi = 0; mi < 4; ++mi)
                a[mi] = *(const bhalf8*)&As[(wy*64 + mi*16 + n16) * 72 + kk*32 + q4*8];
            #pragma unroll
            for (int ni = 0; ni < 4; ++ni)
                b[ni] = *(const bhalf8*)&Bs[(wx*64 + ni*16 + n16) * 72 + kk*32 + q4*8];
            #pragma unroll
            for (int mi = 0; mi < 4; ++mi)
                #pragma unroll
                for (int ni = 0; ni < 4; ++ni)
                    acc[mi][ni] = __builtin_amdgcn_mfma_f32_16x16x32_bf16(
                        a[mi], b[ni], acc[mi][ni], 0, 0, 0);
        }
    }

    if (bn < 1024) {
        #pragma unroll
        for (int mi = 0; mi < 4; ++mi) {
            #pragma unroll
            for (int rr = 0; rr < 4; ++rr) {
                const int row = bm + wy*64 + mi*16 + q4*4 + rr;
                const int b   = row >> 11;
                const int t   = row & (T_ - 1);
                #pragma unroll
                for (int ni = 0; ni < 4; ++ni) {
                    const int col = bn + wx*64 + ni*16 + n16;
                    const u16 val = tob(acc[mi][ni][rr]);
                    if (col < 512) {
                        const int h = col >> 5, r = col & 31;
                        ql[((size_t)(b*H_ + h)*T_ + t)*R_ + r] = val;
                    } else {
                        const int c = col - 512; const int h = c >> 5, r = c & 31;
                        kl[((size_t)(b*H_ + h)*T_ + t)*R_ + r] = val;
                    }
                }
            }
        }
    } else {
        // v: write v_t (B,H,DH,T) directly — 4 consecutive t pack into 8B
        #pragma unroll
        for (int mi = 0; mi < 4; ++mi) {
            const int row0 = bm + wy*64 + mi*16 + q4*4;
            const int b = row0 >> 11;
            const int t = row0 & (T_ - 1);
            #pragma unroll
            for (int ni = 0; ni < 4; ++ni) {
                const int c = bn - 1024 + wx*64 + ni*16 + n16;
                const int h = c >> 6, dh = c & 63;
                uint2 o;
                o.x = pack2(acc[mi][ni][0], acc[mi][ni][1]);
                o.y = pack2(acc[mi][ni][2], acc[mi][ni][3]);
                *(uint2*)(v_t + ((size_t)(b*H_ + h) * DH_ + dh) * T_ + t) = o;
            }
        }
    }
}

// ---------------------------------------------------------------------------
// Kernel 2: MFMA flash attention — 64-row q-tile x 128-col s-tiles.
// Register double-buffer prefetch; conflict-free Ps (stride 144, slot xform).
// ---------------------------------------------------------------------------
__global__ __launch_bounds__(256, 2) void attn_kernel(
    const u16* __restrict__ ql, const u16* __restrict__ kl,
    const u16* __restrict__ v_t, u16* __restrict__ y)
{
    __shared__ __align__(16) u16 qls[64 * 40];
    __shared__ __align__(16) u16 kls[128 * 40];
    __shared__ __align__(16) u16 vsT[64 * 136];
    __shared__ __align__(16) u16 Ps [64 * 144];

    const int tid  = threadIdx.x;
    const int lane = tid & 63;
    const int w    = tid >> 6;
    const int n16  = lane & 15;
    const int q4   = lane >> 4;
    const int bh   = blockIdx.x;
    const int qt   = 31 - (int)blockIdx.y;   // heavy q-tiles first
    const int t0   = qt * 64;
    const int nt   = (qt + 2) >> 1;          // # of 128-wide s-tiles

    {
        const int r = tid >> 2, ch = tid & 3;
        uint4 x = *(const uint4*)(ql + ((size_t)bh * T_ + t0 + r) * R_ + ch*8);
        *(uint4*)&qls[r * 40 + ch*8] = x;
    }
    bhalf8 aq = *(const bhalf8*)&qls[(w*16 + n16) * 40 + q4*8];

    const u16* klb = kl  + (size_t)bh * T_ * R_;
    const u16* vtb = v_t + (size_t)bh * DH_ * T_;
    const int rk = tid >> 2, ck = (tid & 3) * 8;
    const int dv = tid >> 4, cv = (tid & 15) * 8;

    uint4 kc0 = *(const uint4*)(klb + (size_t)(rk     ) * R_ + ck);
    uint4 kc1 = *(const uint4*)(klb + (size_t)(rk + 64) * R_ + ck);
    uint4 vc0 = *(const uint4*)(vtb + (size_t)(dv     ) * T_ + cv);
    uint4 vc1 = *(const uint4*)(vtb + (size_t)(dv + 16) * T_ + cv);
    uint4 vc2 = *(const uint4*)(vtb + (size_t)(dv + 32) * T_ + cv);
    uint4 vc3 = *(const uint4*)(vtb + (size_t)(dv + 48) * T_ + cv);
    uint4 kn0 = kc0, kn1 = kc1, vn0 = vc0, vn1 = vc1, vn2 = vc2, vn3 = vc3;

    float m[4], l[4];
    floatx4 O[4];
    #pragma unroll
    for (int r = 0; r < 4; ++r) { m[r] = NEG_; l[r] = 0.f; }
    #pragma unroll
    for (int c = 0; c < 4; ++c) O[c] = (floatx4)(0.f);

    for (int it = 0; it < nt; ++it) {
        const int s0 = it * 128;
        __syncthreads();
        *(uint4*)&kls[(rk     ) * 40 + ck] = kc0;
        *(uint4*)&kls[(rk + 64) * 40 + ck] = kc1;
        *(uint4*)&vsT[(dv     ) * 136 + cv] = vc0;
        *(uint4*)&vsT[(dv + 16) * 136 + cv] = vc1;
        *(uint4*)&vsT[(dv + 32) * 136 + cv] = vc2;
        *(uint4*)&vsT[(dv + 48) * 136 + cv] = vc3;
        if (it + 1 < nt) {
            const int s1 = s0 + 128;
            kn0 = *(const uint4*)(klb + (size_t)(s1 + rk     ) * R_ + ck);
            kn1 = *(const uint4*)(klb + (size_t)(s1 + rk + 64) * R_ + ck);
            vn0 = *(const uint4*)(vtb + (size_t)(dv     ) * T_ + s1 + cv);
            vn1 = *(const uint4*)(vtb + (size_t)(dv + 16) * T_ + s1 + cv);
            vn2 = *(const uint4*)(vtb + (size_t)(dv + 32) * T_ + s1 + cv);
            vn3 = *(const uint4*)(vtb + (size_t)(dv + 48) * T_ + s1 + cv);
        }
        __syncthreads();

        floatx4 Sc[8];
        #pragma unroll
        for (int c = 0; c < 8; ++c) {
            bhalf8 bk = *(const bhalf8*)&kls[(16*c + n16) * 40 + q4*8];
            Sc[c] = __builtin_amdgcn_mfma_f32_16x16x32_bf16(aq, bk, (floatx4)(0.f), 0, 0, 0);
        }

        if (it == nt - 1) {
            const int tg = t0 + w*16 + q4*4;
            #pragma unroll
            for (int c = 0; c < 8; ++c) {
                const int sg = s0 + 16*c + n16;
                #pragma unroll
                for (int r = 0; r < 4; ++r)
                    if (sg > tg + r) Sc[c][r] = NEG_;
            }
        }

        float rmax[4];
        #pragma unroll
        for (int r = 0; r < 4; ++r) {
            float a0 = fmaxf(fmaxf(Sc[0][r], Sc[1][r]), fmaxf(Sc[2][r], Sc[3][r]));
            float a1 = fmaxf(fmaxf(Sc[4][r], Sc[5][r]), fmaxf(Sc[6][r], Sc[7][r]));
            rmax[r] = fmaxf(a0, a1);
        }
        #pragma unroll
        for (int off = 1; off <= 8; off <<= 1)
            #pragma unroll
            for (int r = 0; r < 4; ++r)
                rmax[r] = fmaxf(rmax[r], __shfl_xor(rmax[r], off, 64));

        float alpha[4], rsum[4];
        #pragma unroll
        for (int r = 0; r < 4; ++r) {
            const float mn = fmaxf(m[r], rmax[r]);
            alpha[r] = __expf(m[r] - mn);
            m[r] = mn;
            rsum[r] = 0.f;
        }
        #pragma unroll
        for (int c = 0; c < 8; ++c)
            #pragma unroll
            for (int r = 0; r < 4; ++r) {
                const float p = __expf(Sc[c][r] - m[r]);
                Sc[c][r] = p;
                rsum[r] += p;
            }
        #pragma unroll
        for (int off = 1; off <= 8; off <<= 1)
            #pragma unroll
            for (int r = 0; r < 4; ++r)
                rsum[r] += __shfl_xor(rsum[r], off, 64);
        #pragma unroll
        for (int r = 0; r < 4; ++r) l[r] = l[r] * alpha[r] + rsum[r];
        #pragma unroll
        for (int c = 0; c < 4; ++c)
            #pragma unroll
            for (int r = 0; r < 4; ++r)
                O[c][r] *= alpha[r];

        #pragma unroll
        for (int c = 0; c < 8; ++c)
            #pragma unroll
            for (int r = 0; r < 4; ++r)
                Ps[(w*16 + r*4 + q4) * 144 + 16*c + n16] = tob(Sc[c][r]);

        const int slot = w*16 + (n16 & 3)*4 + (n16 >> 2);
        #pragma unroll
        for (int kc = 0; kc < 4; ++kc) {
            bhalf8 pa = *(const bhalf8*)&Ps[slot * 144 + kc*32 + q4*8];
            #pragma unroll
            for (int c2 = 0; c2 < 4; ++c2) {
                bhalf8 bv = *(const bhalf8*)&vsT[(16*c2 + n16) * 136 + kc*32 + q4*8];
                O[c2] = __builtin_amdgcn_mfma_f32_16x16x32_bf16(pa, bv, O[c2], 0, 0, 0);
            }
        }

        kc0 = kn0; kc1 = kn1; vc0 = vn0; vc1 = vn1; vc2 = vn2; vc3 = vn3;
    }

    const int b = bh >> 4, h = bh & 15;
    #pragma unroll
    for (int r = 0; r < 4; ++r) {
        const float rl = 1.0f / l[r];
        const int t = t0 + w*16 + q4*4 + r;
        #pragma unroll
        for (int c2 = 0; c2 < 4; ++c2)
            y[((size_t)b * T_ + t) * D_ + h * DH_ + 16*c2 + n16] = tob(O[c2][r] * rl);
    }
}

// ---------------------------------------------------------------------------
// Kernel 3: MFMA out-gemm  yb(4096,1024) @ WoT^T -> out fp32. Reg prefetch.
// ---------------------------------------------------------------------------
__global__ __launch_bounds__(256) void out_gemm_mfma(
    const u16* __restrict__ yb, const u16* __restrict__ WoT,
    float* __restrict__ out)
{
    __shared__ __align__(16) u16 As[128 * 72];
    __shared__ __align__(16) u16 Bs[128 * 72];
    const int tid  = threadIdx.x;
    const int lane = tid & 63;
    const int w    = tid >> 6;
    const int n16  = lane & 15;
    const int q4   = lane >> 4;
    const int wx   = w & 1;
    const int wy   = w >> 1;
    const int bm   = blockIdx.y * 128;
    const int bn   = blockIdx.x * 128;
    const int rs   = tid >> 3;
    const int ch8  = (tid & 7) * 8;

    uint4 pa[4], pb[4];
    #pragma unroll
    for (int p = 0; p < 4; ++p) {
        pa[p] = *(const uint4*)(yb  + (size_t)(bm + rs + 32*p) * D_ + ch8);
        pb[p] = *(const uint4*)(WoT + (size_t)(bn + rs + 32*p) * D_ + ch8);
    }

    floatx4 acc[4][4];
    #pragma unroll
    for (int i = 0; i < 4; ++i)
        #pragma unroll
        for (int j = 0; j < 4; ++j) acc[i][j] = (floatx4)(0.f);

    for (int kt = 0; kt < D_; kt += 64) {
        __syncthreads();
        #pragma unroll
        for (int p = 0; p < 4; ++p) {
            *(uint4*)&As[(rs + 32*p) * 72 + ch8] = pa[p];
            *(uint4*)&Bs[(rs + 32*p) * 72 + ch8] = pb[p];
        }
        if (kt + 64 < D_) {
            #pragma unroll
            for (int p = 0; p < 4; ++p) {
                pa[p] = *(const uint4*)(yb  + (size_t)(bm + rs + 32*p) * D_ + kt + 64 + ch8);
                pb[p] = *(const uint4*)(WoT + (size_t)(bn + rs + 32*p) * D_ + kt + 64 + ch8);
            }
        }
        __syncthreads();
        #pragma unroll
        for (int kk = 0; kk < 2; ++kk) {
            bhalf8 a[4], b[4];
            #pragma unroll
            for (int mi = 0; mi < 4; ++mi)
                a[mi] = *(const bhalf8*)&As[(wy*64 + mi*16 + n16) * 72 + kk*32 + q4*8];
            #pragma unroll
            for (int ni = 0; ni < 4; ++ni)
                b[ni] = *(const bhalf8*)&Bs[(wx*64 + ni*16 + n16) * 72 + kk*32 + q4*8];
            #pragma unroll
            for (int mi = 0; mi < 4; ++mi)
                #pragma unroll
                for (int ni = 0; ni < 4; ++ni)
                    acc[mi][ni] = __builtin_amdgcn_mfma_f32_16x16x32_bf16(
                        a[mi], b[ni], acc[mi][ni], 0, 0, 0);
        }
    }

    #pragma unroll
    for (int mi = 0; mi < 4; ++mi) {
        #pragma unroll
        for (int rr = 0; rr < 4; ++rr) {
            const int row = bm + wy*64 + mi*16 + q4*4 + rr;
            #pragma unroll
            for (int ni = 0; ni < 4; ++ni) {
                const int col = bn + wx*64 + ni*16 + n16;
                out[(size_t)row * D_ + col] = acc[mi][ni][rr];
            }
        }
    }
}

// ---------------------------------------------------------------------------
extern "C" void kernel_launch(void* const* d_in, const int* in_sizes, int n_in,
                              void* d_out, int out_size, void* d_ws, size_t ws_size,
                              hipStream_t stream)
{
    (void)out_size; (void)ws_size;
    const void* in_x = nullptr; const void* in_wqkv = nullptr;
    const void* in_wq = nullptr; const void* in_wk = nullptr;
    const void* in_core = nullptr; const void* in_wo = nullptr;
    for (int i = 0; i < n_in; ++i) {
        const int s = in_sizes[i];
        if      (s == BT_*D_)     { if (!in_x)    in_x    = d_in[i]; }
        else if (s == D_*3*D_)    { if (!in_wqkv) in_wqkv = d_in[i]; }
        else if (s == H_*DH_*R_)  { if (!in_wq)   in_wq   = d_in[i]; else if (!in_wk) in_wk = d_in[i]; }
        else if (s == H_*R_)      { if (!in_core) in_core = d_in[i]; }
        else if (s == D_*D_)      { if (!in_wo)   in_wo   = d_in[i]; }
    }
    if (!in_x)    in_x    = d_in[0];
    if (!in_wqkv) in_wqkv = d_in[1];
    if (!in_wq)   in_wq   = d_in[2];
    if (!in_wk)   in_wk   = d_in[3];
    if (!in_core) in_core = d_in[4];
    if (!in_wo)   in_wo   = d_in[5];

    float* out = (float*)d_out;

    char* ws    = (char*)d_ws;
    int*  flag  = (int*)(ws + WSB_FLAG);
    u16*  xb    = (u16*)(ws + WSB_XB);
    u16*  WcatT = (u16*)(ws + WSB_WCATT);
    u16*  ql    = (u16*)(ws + WSB_QL);
    u16*  kl    = (u16*)(ws + WSB_KL);
    u16*  v_t   = (u16*)(ws + WSB_VT);
    u16*  yb    = (u16*)(ws + WSB_YB);
    u16*  WoT   = (u16*)(ws + WSB_WOT);

    detect_dtype<<<1, 64, 0, stream>>>((const u32*)in_x, flag);
    convert_x<<<2048, 256, 0, stream>>>(in_x, xb, flag);
    fold_mfma<<<dim3(8, 16), 256, 0, stream>>>(in_wqkv, in_wq, in_wk, in_core, WcatT, flag);
    convert_T<<<dim3(16,16), 256, 0, stream>>>(in_wqkv, WcatT, 3*D_, 2*D_, 1024, flag); // W_v
    convert_T<<<dim3(16,16), 256, 0, stream>>>(in_wo,   WoT,   D_,   0,    0,    flag); // W_o
    gemm1_mfma<<<dim3(16, 32), 256, 0, stream>>>(xb, WcatT, ql, kl, v_t);
    attn_kernel<<<dim3(32, 32), 256, 0, stream>>>(ql, kl, v_t, yb);
    out_gemm_mfma<<<dim3(8, 32), 256, 0, stream>>>(yb, WoT, out);
}

// Round 11
// 197.296 us; speedup vs baseline: 1.4125x; 1.4125x over previous
//
#include <hip/hip_runtime.h>
#include <hip/hip_bf16.h>

// Established rounds 0-10: inputs fp32 (detector=insurance), output fp32.
// R5/R6: VALU->MFMA. R7: attn 128-wide s-tiles + conflict-free Ps. R8: fold
// -> MFMA. R10 LESSON: register prefetch before a __syncthreads is DEFEATED
// (barrier emits s_waitcnt vmcnt(0)) and regressed gemm1 70->87us w/ 149MB
// writes -> R11: revert to direct stage->LDS; fix the REAL limiter (TLP):
// 128x64 tiles -> gemm1 1024 blocks (4/CU), out_gemm 512 blocks (2/CU).
#define B_  2
#define T_  2048
#define D_  1024
#define H_  16
#define DH_ 64
#define R_  32
#define BT_ (B_*T_)          // 4096
#define BH_ (B_*H_)          // 32

typedef unsigned short u16;
typedef unsigned int   u32;
typedef __attribute__((ext_vector_type(8))) short bhalf8;   // 8 bf16 = 4 VGPRs
typedef __attribute__((ext_vector_type(4))) float floatx4;  // MFMA C/D

// Workspace layout (bytes). Total ~38 MB.
#define WSB_FLAG  0
#define WSB_XB    256                        // bf16 x     (4096,1024)  8 MB
#define WSB_WCATT (WSB_XB    + 8388608)      // bf16 WcatT (2048,1024)  4 MB
#define WSB_QL    (WSB_WCATT + 4194304)      // bf16 (B,H,T,R)          4 MB
#define WSB_KL    (WSB_QL    + 4194304)      // bf16 (B,H,T,R)          4 MB
#define WSB_VT    (WSB_KL    + 4194304)      // bf16 (B,H,DH,T)         8 MB
#define WSB_YB    (WSB_VT    + 8388608)      // bf16 y     (B,T,D)      8 MB
#define WSB_WOT   (WSB_YB    + 8388608)      // bf16 WoT   (1024,1024)  2 MB

#define NEG_ -1.0e30f

__device__ __forceinline__ float bfs(u16 s) {
    union { u32 i; float f; } w; w.i = ((u32)s) << 16; return w.f;
}
__device__ __forceinline__ u16 tob(float f) {
    __hip_bfloat16 h = __float2bfloat16(f);   // RNE
    return *(u16*)&h;
}
__device__ __forceinline__ u32 pack2(float a, float b) {
    return (u32)tob(a) | ((u32)tob(b) << 16);
}

// ---------------------------------------------------------------------------
// Kernel D: detect input dtype (1 = bf16, 0 = fp32) — insurance only.
// ---------------------------------------------------------------------------
__global__ __launch_bounds__(64) void detect_dtype(const u32* __restrict__ xw,
                                                   int* __restrict__ flag)
{
    const int tid = threadIdx.x;
    int hits = 0;
    for (int i = tid; i < 512; i += 64) {
        const u32 w = xw[i];
        const u32 h = w & 0xFFFFu;
        const u32 e = (h >> 7) & 0xFFu;
        if (h == 0u || (e >= 100u && e <= 150u)) ++hits;
    }
    #pragma unroll
    for (int off = 32; off; off >>= 1) hits += __shfl_down(hits, off, 64);
    if (tid == 0) *flag = (hits >= 300) ? 1 : 0;
}

// ---------------------------------------------------------------------------
// Kernel C: x -> xb bf16 (8 elems/thread). HBM-bound, ~24 MB traffic.
// ---------------------------------------------------------------------------
__global__ __launch_bounds__(256) void convert_x(
    const void* __restrict__ x, u16* __restrict__ xb,
    const int* __restrict__ flag)
{
    const int isbf = *flag;
    const int e = blockIdx.x * 256 + threadIdx.x;  // over 524288 (x8 elems)
    if (isbf) {
        ((uint4*)xb)[e] = ((const uint4*)x)[e];
    } else {
        float4 a0 = ((const float4*)x)[2*e];
        float4 a1 = ((const float4*)x)[2*e + 1];
        uint4 o;
        o.x = pack2(a0.x, a0.y); o.y = pack2(a0.z, a0.w);
        o.z = pack2(a1.x, a1.y); o.w = pack2(a1.z, a1.w);
        ((uint4*)xb)[e] = o;
    }
}

// ---------------------------------------------------------------------------
// Kernel 0: fold via MFMA. Per head h: Cq(32x1024) = Aq_h^T(32x64) @ Wq_h(64x1024)
// with m=r, k=dh, n=d. B operand (Wqkv slice) is k-contiguous natively.
// ---------------------------------------------------------------------------
__global__ __launch_bounds__(256) void fold_mfma(
    const void* __restrict__ Wqkv, const void* __restrict__ Wq_lsr,
    const void* __restrict__ Wk_lsr, const void* __restrict__ core,
    u16* __restrict__ WcatT, const int* __restrict__ flag)
{
    __shared__ __align__(16) u16 Bq[128 * 72];   // [n=d][k=dh]
    __shared__ __align__(16) u16 Bk[128 * 72];
    __shared__ __align__(16) u16 Aq[32 * 72];    // [m=r][k=dh]
    __shared__ __align__(16) u16 Ak[32 * 72];
    const int isbf = *flag;
    const int tid  = threadIdx.x;
    const int lane = tid & 63;
    const int w    = tid >> 6;
    const int n16  = lane & 15;
    const int q4   = lane >> 4;
    const int h    = blockIdx.y;        // 0..15
    const int d0   = blockIdx.x * 128;  // 0..896

    #pragma unroll
    for (int p = 0; p < 8; ++p) {
        const int e  = tid + p * 256;
        const int r  = e & 31, dh = e >> 5;
        float aq, ak;
        if (isbf) {
            aq = bfs(((const u16*)Wq_lsr)[(h*DH_ + dh)*R_ + r]);
            ak = bfs(((const u16*)Wk_lsr)[(h*DH_ + dh)*R_ + r]);
        } else {
            aq = ((const float*)Wq_lsr)[(h*DH_ + dh)*R_ + r];
            ak = ((const float*)Wk_lsr)[(h*DH_ + dh)*R_ + r];
        }
        Aq[r * 72 + dh] = tob(aq);
        Ak[r * 72 + dh] = tob(ak);
    }
    #pragma unroll
    for (int p = 0; p < 8; ++p) {
        const int e  = tid + p * 256;      // 0..2047
        const int n  = e >> 4, ch = e & 15;
        if (isbf) {
            uint2 wq = *(const uint2*)((const u16*)Wqkv + (size_t)(d0+n)*(3*D_) + h*DH_ + ch*4);
            uint2 wk = *(const uint2*)((const u16*)Wqkv + (size_t)(d0+n)*(3*D_) + D_ + h*DH_ + ch*4);
            *(uint2*)&Bq[n * 72 + ch*4] = wq;
            *(uint2*)&Bk[n * 72 + ch*4] = wk;
        } else {
            float4 fq = *(const float4*)((const float*)Wqkv + (size_t)(d0+n)*(3*D_) + h*DH_ + ch*4);
            float4 fk = *(const float4*)((const float*)Wqkv + (size_t)(d0+n)*(3*D_) + D_ + h*DH_ + ch*4);
            uint2 oq, ok;
            oq.x = pack2(fq.x, fq.y); oq.y = pack2(fq.z, fq.w);
            ok.x = pack2(fk.x, fk.y); ok.y = pack2(fk.z, fk.w);
            *(uint2*)&Bq[n * 72 + ch*4] = oq;
            *(uint2*)&Bk[n * 72 + ch*4] = ok;
        }
    }
    __syncthreads();

    floatx4 accq[2][2], acck[2][2];
    #pragma unroll
    for (int mi = 0; mi < 2; ++mi)
        #pragma unroll
        for (int ni = 0; ni < 2; ++ni) { accq[mi][ni] = (floatx4)(0.f); acck[mi][ni] = (floatx4)(0.f); }

    #pragma unroll
    for (int kk = 0; kk < 2; ++kk) {
        bhalf8 aqf[2], akf[2], bqf[2], bkf[2];
        #pragma unroll
        for (int mi = 0; mi < 2; ++mi) {
            aqf[mi] = *(const bhalf8*)&Aq[(mi*16 + n16) * 72 + kk*32 + q4*8];
            akf[mi] = *(const bhalf8*)&Ak[(mi*16 + n16) * 72 + kk*32 + q4*8];
        }
        #pragma unroll
        for (int ni = 0; ni < 2; ++ni) {
            bqf[ni] = *(const bhalf8*)&Bq[(w*32 + ni*16 + n16) * 72 + kk*32 + q4*8];
            bkf[ni] = *(const bhalf8*)&Bk[(w*32 + ni*16 + n16) * 72 + kk*32 + q4*8];
        }
        #pragma unroll
        for (int mi = 0; mi < 2; ++mi)
            #pragma unroll
            for (int ni = 0; ni < 2; ++ni) {
                accq[mi][ni] = __builtin_amdgcn_mfma_f32_16x16x32_bf16(aqf[mi], bqf[ni], accq[mi][ni], 0, 0, 0);
                acck[mi][ni] = __builtin_amdgcn_mfma_f32_16x16x32_bf16(akf[mi], bkf[ni], acck[mi][ni], 0, 0, 0);
            }
    }

    const float scale = 0.17677669529663687f;  // 1/sqrt(32)
    #pragma unroll
    for (int mi = 0; mi < 2; ++mi) {
        #pragma unroll
        for (int rr = 0; rr < 4; ++rr) {
            const int r = mi*16 + q4*4 + rr;
            const float cc = (isbf ? bfs(((const u16*)core)[h*R_ + r])
                                   : ((const float*)core)[h*R_ + r]) * scale;
            #pragma unroll
            for (int ni = 0; ni < 2; ++ni) {
                const int d = d0 + w*32 + ni*16 + n16;
                WcatT[(size_t)(h*R_ + r) * D_ + d]       = tob(accq[mi][ni][rr] * cc);
                WcatT[(size_t)(512 + h*R_ + r) * D_ + d] = tob(acck[mi][ni][rr]);
            }
        }
    }
}

// ---------------------------------------------------------------------------
// Kernel T: generic transposing convert (fp32/bf16 -> bf16), 64x64 tiles.
// ---------------------------------------------------------------------------
__global__ __launch_bounds__(256) void convert_T(
    const void* __restrict__ src, u16* __restrict__ dst,
    int srcStride, int srcColOff, int dstRowOff, const int* __restrict__ flag)
{
    __shared__ __align__(16) u16 tile[64 * 72];
    const int isbf = *flag;
    const int tid = threadIdx.x;
    const int j0  = blockIdx.x * 64;
    const int i0  = blockIdx.y * 64;
    #pragma unroll
    for (int p = 0; p < 2; ++p) {
        const int e = tid + p * 256;
        const int r = e >> 3, ch = e & 7;
        if (isbf) {
            uint4 w = *(const uint4*)((const u16*)src + (size_t)(i0 + r) * srcStride + srcColOff + j0 + ch*8);
            *(uint4*)&tile[r * 72 + ch*8] = w;
        } else {
            const float* s = (const float*)src + (size_t)(i0 + r) * srcStride + srcColOff + j0 + ch*8;
            float4 a0 = *(const float4*)s;
            float4 a1 = *(const float4*)(s + 4);
            uint4 o;
            o.x = pack2(a0.x, a0.y); o.y = pack2(a0.z, a0.w);
            o.z = pack2(a1.x, a1.y); o.w = pack2(a1.z, a1.w);
            *(uint4*)&tile[r * 72 + ch*8] = o;
        }
    }
    __syncthreads();
    #pragma unroll
    for (int p = 0; p < 2; ++p) {
        const int e = tid + p * 256;
        const int c = e >> 3, ch = e & 7;
        u16 tmp[8];
        #pragma unroll
        for (int j = 0; j < 8; ++j) tmp[j] = tile[(ch*8 + j) * 72 + c];
        *(uint4*)(dst + (size_t)(dstRowOff + j0 + c) * D_ + i0 + ch*8) = *(uint4*)tmp;
    }
}

// ---------------------------------------------------------------------------
// Kernel 1: MFMA gemm1  xb(4096,1024) @ WcatT^T -> ql/kl + v_t.
// 128x64 tile, BK=64, 4 waves 2x2 (wave = 64m x 32n, acc[4][2]).
// Grid (32 bn, 32 bm) = 1024 blocks = 4/CU: TLP hides the barrier drain.
// Direct stage->LDS (no reg prefetch — defeated by barrier vmcnt(0) drain).
// ---------------------------------------------------------------------------
__global__ __launch_bounds__(256) void gemm1_mfma(
    const u16* __restrict__ xb, const u16* __restrict__ WcatT,
    u16* __restrict__ ql, u16* __restrict__ kl, u16* __restrict__ v_t)
{
    __shared__ __align__(16) u16 As[128 * 72];   // 18432 B
    __shared__ __align__(16) u16 Bs[64 * 72];    //  9216 B
    const int tid  = threadIdx.x;
    const int lane = tid & 63;
    const int w    = tid >> 6;
    const int n16  = lane & 15;
    const int q4   = lane >> 4;
    const int wx   = w & 1;          // n-half (32 cols)
    const int wy   = w >> 1;         // m-half (64 rows)
    const int bm   = blockIdx.y * 128;
    const int bn   = blockIdx.x * 64;

    floatx4 acc[4][2];
    #pragma unroll
    for (int i = 0; i < 4; ++i)
        #pragma unroll
        for (int j = 0; j < 2; ++j) acc[i][j] = (floatx4)(0.f);

    for (int kt = 0; kt < D_; kt += 64) {
        #pragma unroll
        for (int p = 0; p < 4; ++p) {
            const int e = tid + p * 256;       // 0..1023
            const int r = e >> 3, ch = (e & 7) * 8;
            *(uint4*)&As[r * 72 + ch] = *(const uint4*)(xb + (size_t)(bm + r) * D_ + kt + ch);
        }
        #pragma unroll
        for (int p = 0; p < 2; ++p) {
            const int e = tid + p * 256;       // 0..511
            const int r = e >> 3, ch = (e & 7) * 8;
            *(uint4*)&Bs[r * 72 + ch] = *(const uint4*)(WcatT + (size_t)(bn + r) * D_ + kt + ch);
        }
        __syncthreads();
        #pragma unroll
        for (int kk = 0; kk < 2; ++kk) {
            bhalf8 a[4], b[2];
            #pragma unroll
            for (int mi = 0; mi < 4; ++mi)
                a[mi] = *(const bhalf8*)&As[(wy*64 + mi*16 + n16) * 72 + kk*32 + q4*8];
            #pragma unroll
            for (int ni = 0; ni < 2; ++ni)
                b[ni] = *(const bhalf8*)&Bs[(wx*32 + ni*16 + n16) * 72 + kk*32 + q4*8];
            #pragma unroll
            for (int mi = 0; mi < 4; ++mi)
                #pragma unroll
                for (int ni = 0; ni < 2; ++ni)
                    acc[mi][ni] = __builtin_amdgcn_mfma_f32_16x16x32_bf16(
                        a[mi], b[ni], acc[mi][ni], 0, 0, 0);
        }
        __syncthreads();
    }

    if (bn < 1024) {
        #pragma unroll
        for (int mi = 0; mi < 4; ++mi) {
            #pragma unroll
            for (int rr = 0; rr < 4; ++rr) {
                const int row = bm + wy*64 + mi*16 + q4*4 + rr;
                const int b   = row >> 11;
                const int t   = row & (T_ - 1);
                #pragma unroll
                for (int ni = 0; ni < 2; ++ni) {
                    const int col = bn + wx*32 + ni*16 + n16;
                    const u16 val = tob(acc[mi][ni][rr]);
                    if (col < 512) {
                        const int h = col >> 5, r = col & 31;
                        ql[((size_t)(b*H_ + h)*T_ + t)*R_ + r] = val;
                    } else {
                        const int c = col - 512; const int h = c >> 5, r = c & 31;
                        kl[((size_t)(b*H_ + h)*T_ + t)*R_ + r] = val;
                    }
                }
            }
        }
    } else {
        // v: write v_t (B,H,DH,T) directly — 4 consecutive t pack into 8B
        #pragma unroll
        for (int mi = 0; mi < 4; ++mi) {
            const int row0 = bm + wy*64 + mi*16 + q4*4;
            const int b = row0 >> 11;
            const int t = row0 & (T_ - 1);
            #pragma unroll
            for (int ni = 0; ni < 2; ++ni) {
                const int c = bn - 1024 + wx*32 + ni*16 + n16;
                const int h = c >> 6, dh = c & 63;
                uint2 o;
                o.x = pack2(acc[mi][ni][0], acc[mi][ni][1]);
                o.y = pack2(acc[mi][ni][2], acc[mi][ni][3]);
                *(uint2*)(v_t + ((size_t)(b*H_ + h) * DH_ + dh) * T_ + t) = o;
            }
        }
    }
}

// ---------------------------------------------------------------------------
// Kernel 2: MFMA flash attention — 64-row q-tile x 128-col s-tiles.
// (unchanged from R9/R10 — ~65us, conflict-free Ps, stable)
// ---------------------------------------------------------------------------
__global__ __launch_bounds__(256, 2) void attn_kernel(
    const u16* __restrict__ ql, const u16* __restrict__ kl,
    const u16* __restrict__ v_t, u16* __restrict__ y)
{
    __shared__ __align__(16) u16 qls[64 * 40];
    __shared__ __align__(16) u16 kls[128 * 40];
    __shared__ __align__(16) u16 vsT[64 * 136];
    __shared__ __align__(16) u16 Ps [64 * 144];

    const int tid  = threadIdx.x;
    const int lane = tid & 63;
    const int w    = tid >> 6;
    const int n16  = lane & 15;
    const int q4   = lane >> 4;
    const int bh   = blockIdx.x;
    const int qt   = 31 - (int)blockIdx.y;   // heavy q-tiles first
    const int t0   = qt * 64;
    const int nt   = (qt + 2) >> 1;          // # of 128-wide s-tiles

    {
        const int r = tid >> 2, ch = tid & 3;
        uint4 x = *(const uint4*)(ql + ((size_t)bh * T_ + t0 + r) * R_ + ch*8);
        *(uint4*)&qls[r * 40 + ch*8] = x;
    }
    bhalf8 aq = *(const bhalf8*)&qls[(w*16 + n16) * 40 + q4*8];

    const u16* klb = kl  + (size_t)bh * T_ * R_;
    const u16* vtb = v_t + (size_t)bh * DH_ * T_;
    const int rk = tid >> 2, ck = (tid & 3) * 8;
    const int dv = tid >> 4, cv = (tid & 15) * 8;

    uint4 kc0 = *(const uint4*)(klb + (size_t)(rk     ) * R_ + ck);
    uint4 kc1 = *(const uint4*)(klb + (size_t)(rk + 64) * R_ + ck);
    uint4 vc0 = *(const uint4*)(vtb + (size_t)(dv     ) * T_ + cv);
    uint4 vc1 = *(const uint4*)(vtb + (size_t)(dv + 16) * T_ + cv);
    uint4 vc2 = *(const uint4*)(vtb + (size_t)(dv + 32) * T_ + cv);
    uint4 vc3 = *(const uint4*)(vtb + (size_t)(dv + 48) * T_ + cv);
    uint4 kn0 = kc0, kn1 = kc1, vn0 = vc0, vn1 = vc1, vn2 = vc2, vn3 = vc3;

    float m[4], l[4];
    floatx4 O[4];
    #pragma unroll
    for (int r = 0; r < 4; ++r) { m[r] = NEG_; l[r] = 0.f; }
    #pragma unroll
    for (int c = 0; c < 4; ++c) O[c] = (floatx4)(0.f);

    for (int it = 0; it < nt; ++it) {
        const int s0 = it * 128;
        __syncthreads();
        *(uint4*)&kls[(rk     ) * 40 + ck] = kc0;
        *(uint4*)&kls[(rk + 64) * 40 + ck] = kc1;
        *(uint4*)&vsT[(dv     ) * 136 + cv] = vc0;
        *(uint4*)&vsT[(dv + 16) * 136 + cv] = vc1;
        *(uint4*)&vsT[(dv + 32) * 136 + cv] = vc2;
        *(uint4*)&vsT[(dv + 48) * 136 + cv] = vc3;
        if (it + 1 < nt) {
            const int s1 = s0 + 128;
            kn0 = *(const uint4*)(klb + (size_t)(s1 + rk     ) * R_ + ck);
            kn1 = *(const uint4*)(klb + (size_t)(s1 + rk + 64) * R_ + ck);
            vn0 = *(const uint4*)(vtb + (size_t)(dv     ) * T_ + s1 + cv);
            vn1 = *(const uint4*)(vtb + (size_t)(dv + 16) * T_ + s1 + cv);
            vn2 = *(const uint4*)(vtb + (size_t)(dv + 32) * T_ + s1 + cv);
            vn3 = *(const uint4*)(vtb + (size_t)(dv + 48) * T_ + s1 + cv);
        }
        __syncthreads();

        floatx4 Sc[8];
        #pragma unroll
        for (int c = 0; c < 8; ++c) {
            bhalf8 bk = *(const bhalf8*)&kls[(16*c + n16) * 40 + q4*8];
            Sc[c] = __builtin_amdgcn_mfma_f32_16x16x32_bf16(aq, bk, (floatx4)(0.f), 0, 0, 0);
        }

        if (it == nt - 1) {
            const int tg = t0 + w*16 + q4*4;
            #pragma unroll
            for (int c = 0; c < 8; ++c) {
                const int sg = s0 + 16*c + n16;
                #pragma unroll
                for (int r = 0; r < 4; ++r)
                    if (sg > tg + r) Sc[c][r] = NEG_;
            }
        }

        float rmax[4];
        #pragma unroll
        for (int r = 0; r < 4; ++r) {
            float a0 = fmaxf(fmaxf(Sc[0][r], Sc[1][r]), fmaxf(Sc[2][r], Sc[3][r]));
            float a1 = fmaxf(fmaxf(Sc[4][r], Sc[5][r]), fmaxf(Sc[6][r], Sc[7][r]));
            rmax[r] = fmaxf(a0, a1);
        }
        #pragma unroll
        for (int off = 1; off <= 8; off <<= 1)
            #pragma unroll
            for (int r = 0; r < 4; ++r)
                rmax[r] = fmaxf(rmax[r], __shfl_xor(rmax[r], off, 64));

        float alpha[4], rsum[4];
        #pragma unroll
        for (int r = 0; r < 4; ++r) {
            const float mn = fmaxf(m[r], rmax[r]);
            alpha[r] = __expf(m[r] - mn);
            m[r] = mn;
            rsum[r] = 0.f;
        }
        #pragma unroll
        for (int c = 0; c < 8; ++c)
            #pragma unroll
            for (int r = 0; r < 4; ++r) {
                const float p = __expf(Sc[c][r] - m[r]);
                Sc[c][r] = p;
                rsum[r] += p;
            }
        #pragma unroll
        for (int off = 1; off <= 8; off <<= 1)
            #pragma unroll
            for (int r = 0; r < 4; ++r)
                rsum[r] += __shfl_xor(rsum[r], off, 64);
        #pragma unroll
        for (int r = 0; r < 4; ++r) l[r] = l[r] * alpha[r] + rsum[r];
        #pragma unroll
        for (int c = 0; c < 4; ++c)
            #pragma unroll
            for (int r = 0; r < 4; ++r)
                O[c][r] *= alpha[r];

        #pragma unroll
        for (int c = 0; c < 8; ++c)
            #pragma unroll
            for (int r = 0; r < 4; ++r)
                Ps[(w*16 + r*4 + q4) * 144 + 16*c + n16] = tob(Sc[c][r]);

        const int slot = w*16 + (n16 & 3)*4 + (n16 >> 2);
        #pragma unroll
        for (int kc = 0; kc < 4; ++kc) {
            bhalf8 pa = *(const bhalf8*)&Ps[slot * 144 + kc*32 + q4*8];
            #pragma unroll
            for (int c2 = 0; c2 < 4; ++c2) {
                bhalf8 bv = *(const bhalf8*)&vsT[(16*c2 + n16) * 136 + kc*32 + q4*8];
                O[c2] = __builtin_amdgcn_mfma_f32_16x16x32_bf16(pa, bv, O[c2], 0, 0, 0);
            }
        }

        kc0 = kn0; kc1 = kn1; vc0 = vn0; vc1 = vn1; vc2 = vn2; vc3 = vn3;
    }

    const int b = bh >> 4, h = bh & 15;
    #pragma unroll
    for (int r = 0; r < 4; ++r) {
        const float rl = 1.0f / l[r];
        const int t = t0 + w*16 + q4*4 + r;
        #pragma unroll
        for (int c2 = 0; c2 < 4; ++c2)
            y[((size_t)b * T_ + t) * D_ + h * DH_ + 16*c2 + n16] = tob(O[c2][r] * rl);
    }
}

// ---------------------------------------------------------------------------
// Kernel 3: MFMA out-gemm  yb(4096,1024) @ WoT^T -> out fp32.
// 128x64 tile -> grid (16,32) = 512 blocks = 2/CU (was 1/CU). Direct staging.
// ---------------------------------------------------------------------------
__global__ __launch_bounds__(256) void out_gemm_mfma(
    const u16* __restrict__ yb, const u16* __restrict__ WoT,
    float* __restrict__ out)
{
    __shared__ __align__(16) u16 As[128 * 72];
    __shared__ __align__(16) u16 Bs[64 * 72];
    const int tid  = threadIdx.x;
    const int lane = tid & 63;
    const int w    = tid >> 6;
    const int n16  = lane & 15;
    const int q4   = lane >> 4;
    const int wx   = w & 1;
    const int wy   = w >> 1;
    const int bm   = blockIdx.y * 128;
    const int bn   = blockIdx.x * 64;

    floatx4 acc[4][2];
    #pragma unroll
    for (int i = 0; i < 4; ++i)
        #pragma unroll
        for (int j = 0; j < 2; ++j) acc[i][j] = (floatx4)(0.f);

    for (int kt = 0; kt < D_; kt += 64) {
        #pragma unroll
        for (int p = 0; p < 4; ++p) {
            const int e = tid + p * 256;
            const int r = e >> 3, ch = (e & 7) * 8;
            *(uint4*)&As[r * 72 + ch] = *(const uint4*)(yb + (size_t)(bm + r) * D_ + kt + ch);
        }
        #pragma unroll
        for (int p = 0; p < 2; ++p) {
            const int e = tid + p * 256;
            const int r = e >> 3, ch = (e & 7) * 8;
            *(uint4*)&Bs[r * 72 + ch] = *(const uint4*)(WoT + (size_t)(bn + r) * D_ + kt + ch);
        }
        __syncthreads();
        #pragma unroll
        for (int kk = 0; kk < 2; ++kk) {
            bhalf8 a[4], b[2];
            #pragma unroll
            for (int mi = 0; mi < 4; ++mi)
                a[mi] = *(const bhalf8*)&As[(wy*64 + mi*16 + n16) * 72 + kk*32 + q4*8];
            #pragma unroll
            for (int ni = 0; ni < 2; ++ni)
                b[ni] = *(const bhalf8*)&Bs[(wx*32 + ni*16 + n16) * 72 + kk*32 + q4*8];
            #pragma unroll
            for (int mi = 0; mi < 4; ++mi)
                #pragma unroll
                for (int ni = 0; ni < 2; ++ni)
                    acc[mi][ni] = __builtin_amdgcn_mfma_f32_16x16x32_bf16(
                        a[mi], b[ni], acc[mi][ni], 0, 0, 0);
        }
        __syncthreads();
    }

    #pragma unroll
    for (int mi = 0; mi < 4; ++mi) {
        #pragma unroll
        for (int rr = 0; rr < 4; ++rr) {
            const int row = bm + wy*64 + mi*16 + q4*4 + rr;
            #pragma unroll
            for (int ni = 0; ni < 2; ++ni) {
                const int col = bn + wx*32 + ni*16 + n16;
                out[(size_t)row * D_ + col] = acc[mi][ni][rr];
            }
        }
    }
}

// ---------------------------------------------------------------------------
extern "C" void kernel_launch(void* const* d_in, const int* in_sizes, int n_in,
                              void* d_out, int out_size, void* d_ws, size_t ws_size,
                              hipStream_t stream)
{
    (void)out_size; (void)ws_size;
    const void* in_x = nullptr; const void* in_wqkv = nullptr;
    const void* in_wq = nullptr; const void* in_wk = nullptr;
    const void* in_core = nullptr; const void* in_wo = nullptr;
    for (int i = 0; i < n_in; ++i) {
        const int s = in_sizes[i];
        if      (s == BT_*D_)     { if (!in_x)    in_x    = d_in[i]; }
        else if (s == D_*3*D_)    { if (!in_wqkv) in_wqkv = d_in[i]; }
        else if (s == H_*DH_*R_)  { if (!in_wq)   in_wq   = d_in[i]; else if (!in_wk) in_wk = d_in[i]; }
        else if (s == H_*R_)      { if (!in_core) in_core = d_in[i]; }
        else if (s == D_*D_)      { if (!in_wo)   in_wo   = d_in[i]; }
    }
    if (!in_x)    in_x    = d_in[0];
    if (!in_wqkv) in_wqkv = d_in[1];
    if (!in_wq)   in_wq   = d_in[2];
    if (!in_wk)   in_wk   = d_in[3];
    if (!in_core) in_core = d_in[4];
    if (!in_wo)   in_wo   = d_in[5];

    float* out = (float*)d_out;

    char* ws    = (char*)d_ws;
    int*  flag  = (int*)(ws + WSB_FLAG);
    u16*  xb    = (u16*)(ws + WSB_XB);
    u16*  WcatT = (u16*)(ws + WSB_WCATT);
    u16*  ql    = (u16*)(ws + WSB_QL);
    u16*  kl    = (u16*)(ws + WSB_KL);
    u16*  v_t   = (u16*)(ws + WSB_VT);
    u16*  yb    = (u16*)(ws + WSB_YB);
    u16*  WoT   = (u16*)(ws + WSB_WOT);

    detect_dtype<<<1, 64, 0, stream>>>((const u32*)in_x, flag);
    convert_x<<<2048, 256, 0, stream>>>(in_x, xb, flag);
    fold_mfma<<<dim3(8, 16), 256, 0, stream>>>(in_wqkv, in_wq, in_wk, in_core, WcatT, flag);
    convert_T<<<dim3(16,16), 256, 0, stream>>>(in_wqkv, WcatT, 3*D_, 2*D_, 1024, flag); // W_v
    convert_T<<<dim3(16,16), 256, 0, stream>>>(in_wo,   WoT,   D_,   0,    0,    flag); // W_o
    gemm1_mfma<<<dim3(32, 32), 256, 0, stream>>>(xb, WcatT, ql, kl, v_t);
    attn_kernel<<<dim3(32, 32), 256, 0, stream>>>(ql, kl, v_t, yb);
    out_gemm_mfma<<<dim3(16, 32), 256, 0, stream>>>(yb, WoT, out);
}